// Round 3
// baseline (774.462 us; speedup 1.0000x reference)
//
#include <hip/hip_runtime.h>

#define N_IN_SZ   400000
#define N_OUT_SZ  200000
#define K_OFF     27
#define R_RULES   200000
#define NC        32
#define RPB       64          // rules per block (per k-offset)

typedef unsigned int       u32;
typedef unsigned long long u64;

#define FXS   1048576.0f      // 2^20 fixed-point scale
#define FBIAS 16777216u       // 2^24 per-add bias (keeps halves positive)

// ws layout: [0, 25.6MB) u64 accum (N_OUT*16), then u32 cnt[N_OUT]
#define WS64_WORDS   (N_OUT_SZ * 16)                  // 3.2M u64
#define CNT_OFFSET   ((size_t)WS64_WORDS * 8)         // 25,600,000 B
#define WS_NEEDED    (CNT_OFFSET + (size_t)N_OUT_SZ * 4)

// ---------------------------------------------------------------------------
// zero ws (accumulators + counts). 6.6M u32 = 1.65M uint4.
// ---------------------------------------------------------------------------
__global__ __launch_bounds__(256) void zero_ws_kernel(uint4* __restrict__ ws)
{
    const int total = (WS64_WORDS * 2 + N_OUT_SZ) / 4;   // 1,650,000
    int idx = blockIdx.x * 256 + threadIdx.x;
    if (idx < total) ws[idx] = make_uint4(0, 0, 0, 0);
}

// ---------------------------------------------------------------------------
// conv scatter, packed u64 fixed-point atomics.
// 16-lane group per rule; lane j handles channels (2j, 2j+1).
// ---------------------------------------------------------------------------
__global__ __launch_bounds__(256) void conv_scatter_u64_kernel(
    const float* __restrict__ feat,     // [N_IN, 32]
    const float* __restrict__ weight,   // [27*32, 32]
    const int*   __restrict__ in_idx,   // [27, R]
    const int*   __restrict__ out_idx,  // [27, R]
    u64*         __restrict__ acc64,    // [N_OUT, 16]
    u32*         __restrict__ cnt)      // [N_OUT]
{
    __shared__ float2 Wlds[NC * 16];    // Wlds[i*16+j] = (W[k][i][2j], W[k][i][2j+1])

    const int k = blockIdx.y;
    const float2* wg = reinterpret_cast<const float2*>(weight + k * NC * NC);
    for (int t = threadIdx.x; t < NC * 16; t += 256)
        Wlds[t] = wg[t];
    __syncthreads();

    const int j = threadIdx.x & 15;     // channel-pair id
    const int g = threadIdx.x >> 4;     // rule-group id (0..15)

    // hoist this lane's two weight columns into registers (64 floats)
    float2 wcol[NC];
#pragma unroll
    for (int i = 0; i < NC; ++i)
        wcol[i] = Wlds[i * 16 + j];

    const int rbase = blockIdx.x * RPB;

    for (int rr = g; rr < RPB; rr += 16) {
        const int r = rbase + rr;
        const int irow = in_idx[k * R_RULES + r];
        const int orow = out_idx[k * R_RULES + r];

        const float4* fv = reinterpret_cast<const float4*>(feat + (size_t)irow * NC);

        float a0 = 0.0f, a1 = 0.0f;
#pragma unroll
        for (int i0 = 0; i0 < 8; ++i0) {
            const float4 f = fv[i0];    // broadcast within 16-lane group
            a0 += f.x * wcol[i0 * 4 + 0].x;  a1 += f.x * wcol[i0 * 4 + 0].y;
            a0 += f.y * wcol[i0 * 4 + 1].x;  a1 += f.y * wcol[i0 * 4 + 1].y;
            a0 += f.z * wcol[i0 * 4 + 2].x;  a1 += f.z * wcol[i0 * 4 + 2].y;
            a0 += f.w * wcol[i0 * 4 + 3].x;  a1 += f.w * wcol[i0 * 4 + 3].y;
        }

        const int q0 = __float2int_rn(a0 * FXS);
        const int q1 = __float2int_rn(a1 * FXS);
        const u64 p = ((u64)(u32)(q1 + (int)FBIAS) << 32) | (u64)(u32)(q0 + (int)FBIAS);

        // lanes 0..15 -> 16 consecutive u64 = one contiguous 128B row
        atomicAdd(acc64 + (size_t)orow * 16 + j, p);
        if (j == 0) atomicAdd(cnt + orow, 1u);
    }
}

// ---------------------------------------------------------------------------
// unpack: out[o][2j..2j+1] = (half - cnt*FBIAS)/FXS + bias
// ---------------------------------------------------------------------------
__global__ __launch_bounds__(256) void unpack_kernel(
    const u64* __restrict__ acc64, const u32* __restrict__ cnt,
    const float* __restrict__ bias, float* __restrict__ out)
{
    int t = blockIdx.x * 256 + threadIdx.x;      // u64 index
    if (t >= WS64_WORDS) return;
    const int row = t >> 4;
    const int j   = t & 15;
    const u64 w   = acc64[t];
    const u32 c   = cnt[row];
    const u32 sub = c * FBIAS;
    const int v0  = (int)((u32)w - sub);
    const int v1  = (int)((u32)(w >> 32) - sub);
    const float2 b = reinterpret_cast<const float2*>(bias)[j];
    float2 o;
    o.x = (float)v0 * (1.0f / FXS) + b.x;
    o.y = (float)v1 * (1.0f / FXS) + b.y;
    reinterpret_cast<float2*>(out)[t] = o;
}

// ===========================================================================
// Fallback path (ws too small): round-2 f32 atomic version
// ===========================================================================
__global__ __launch_bounds__(256) void init_out_kernel(
    const float* __restrict__ bias, float* __restrict__ out)
{
    int idx = blockIdx.x * 256 + threadIdx.x;
    const int total4 = N_OUT_SZ * NC / 4;
    if (idx >= total4) return;
    int c0 = (idx * 4) & (NC - 1);
    float4 b;
    b.x = bias[c0 + 0]; b.y = bias[c0 + 1]; b.z = bias[c0 + 2]; b.w = bias[c0 + 3];
    reinterpret_cast<float4*>(out)[idx] = b;
}

__global__ __launch_bounds__(256) void conv_scatter_kernel(
    const float* __restrict__ feat, const float* __restrict__ weight,
    const int* __restrict__ in_idx, const int* __restrict__ out_idx,
    float* __restrict__ out)
{
    __shared__ float Wlds[NC * NC];
    const int k  = blockIdx.y;
    const int c  = threadIdx.x & (NC - 1);
    const int rg = threadIdx.x >> 5;
    for (int t = threadIdx.x; t < NC * NC; t += 256)
        Wlds[t] = weight[k * NC * NC + t];
    __syncthreads();
    float wcol[NC];
#pragma unroll
    for (int i = 0; i < NC; ++i) wcol[i] = Wlds[i * NC + c];
    const int rbase = blockIdx.x * RPB;
    for (int rr = rg; rr < RPB; rr += 8) {
        const int r = rbase + rr;
        const int irow = in_idx[k * R_RULES + r];
        const int orow = out_idx[k * R_RULES + r];
        const float4* fv = reinterpret_cast<const float4*>(feat + (size_t)irow * NC);
        float acc = 0.0f;
#pragma unroll
        for (int i0 = 0; i0 < 8; ++i0) {
            const float4 f = fv[i0];
            acc += f.x * wcol[i0 * 4 + 0];
            acc += f.y * wcol[i0 * 4 + 1];
            acc += f.z * wcol[i0 * 4 + 2];
            acc += f.w * wcol[i0 * 4 + 3];
        }
        atomicAdd(out + (size_t)orow * NC + c, acc);
    }
}

// ---------------------------------------------------------------------------
extern "C" void kernel_launch(void* const* d_in, const int* in_sizes, int n_in,
                              void* d_out, int out_size, void* d_ws, size_t ws_size,
                              hipStream_t stream)
{
    const float* feat    = (const float*)d_in[0];
    const float* weight  = (const float*)d_in[1];
    const float* bias    = (const float*)d_in[2];
    const int*   in_idx  = (const int*)d_in[3];
    const int*   out_idx = (const int*)d_in[4];
    float*       out     = (float*)d_out;

    if (ws_size >= WS_NEEDED) {
        u64* acc64 = (u64*)d_ws;
        u32* cnt   = (u32*)((char*)d_ws + CNT_OFFSET);

        {   // zero accumulators + counts
            int total = (WS64_WORDS * 2 + N_OUT_SZ) / 4;
            zero_ws_kernel<<<(total + 255) / 256, 256, 0, stream>>>((uint4*)d_ws);
        }
        {   // packed u64 fixed-point scatter
            dim3 grid(R_RULES / RPB, K_OFF);
            conv_scatter_u64_kernel<<<grid, 256, 0, stream>>>(
                feat, weight, in_idx, out_idx, acc64, cnt);
        }
        {   // unpack to f32 + bias
            unpack_kernel<<<WS64_WORDS / 256, 256, 0, stream>>>(acc64, cnt, bias, out);
        }
    } else {
        // fallback: f32 atomic scatter
        {
            int total4 = N_OUT_SZ * NC / 4;
            init_out_kernel<<<(total4 + 255) / 256, 256, 0, stream>>>(bias, out);
        }
        {
            dim3 grid(R_RULES / RPB, K_OFF);
            conv_scatter_kernel<<<grid, 256, 0, stream>>>(feat, weight, in_idx, out_idx, out);
        }
    }
}

// Round 4
// 634.110 us; speedup vs baseline: 1.2213x; 1.2213x over previous
//
#include <hip/hip_runtime.h>
#include <hip/hip_fp16.h>

#define N_IN_SZ   400000
#define N_OUT_SZ  200000
#define K_OFF     27
#define R_RULES   200000
#define NC        32
#define RPB       64          // rules per block (per k-offset)

typedef unsigned int u32;

// ws layout: __half2 acc[N_OUT * 16]  (12.8 MB)
#define ACC_WORDS  (N_OUT_SZ * 16)                 // 3.2M __half2 (u32 each)
#define WS_NEEDED  ((size_t)ACC_WORDS * 4)

// ---------------------------------------------------------------------------
// zero ws accumulators: 3.2M u32 = 800K uint4
// ---------------------------------------------------------------------------
__global__ __launch_bounds__(256) void zero_ws_kernel(uint4* __restrict__ ws)
{
    const int total = ACC_WORDS / 4;               // 800,000
    int idx = blockIdx.x * 256 + threadIdx.x;
    if (idx < total) ws[idx] = make_uint4(0, 0, 0, 0);
}

// ---------------------------------------------------------------------------
// conv scatter with packed-f16 atomics (global_atomic_pk_add_f16).
// 16-lane group per rule; lane j handles channels (2j, 2j+1).
// One dword atomic carries TWO channels -> half the atomic payload of f32.
// ---------------------------------------------------------------------------
__global__ __launch_bounds__(256) void conv_scatter_f16_kernel(
    const float* __restrict__ feat,     // [N_IN, 32]
    const float* __restrict__ weight,   // [27*32, 32]
    const int*   __restrict__ in_idx,   // [27, R]
    const int*   __restrict__ out_idx,  // [27, R]
    __half2*     __restrict__ acc)      // [N_OUT, 16]
{
    __shared__ float2 Wlds[NC * 16];    // Wlds[i*16+j] = (W[k][i][2j], W[k][i][2j+1])

    const int k = blockIdx.y;
    const float2* wg = reinterpret_cast<const float2*>(weight + k * NC * NC);
    for (int t = threadIdx.x; t < NC * 16; t += 256)
        Wlds[t] = wg[t];
    __syncthreads();

    const int j = threadIdx.x & 15;     // channel-pair id
    const int g = threadIdx.x >> 4;     // rule-group id (0..15)

    // hoist this lane's two weight columns into registers (64 floats)
    float2 wcol[NC];
#pragma unroll
    for (int i = 0; i < NC; ++i)
        wcol[i] = Wlds[i * 16 + j];

    const int rbase = blockIdx.x * RPB;

    for (int rr = g; rr < RPB; rr += 16) {
        const int r = rbase + rr;
        const int irow = in_idx[k * R_RULES + r];
        const int orow = out_idx[k * R_RULES + r];

        const float4* fv = reinterpret_cast<const float4*>(feat + (size_t)irow * NC);

        float a0 = 0.0f, a1 = 0.0f;
#pragma unroll
        for (int i0 = 0; i0 < 8; ++i0) {
            const float4 f = fv[i0];    // broadcast within 16-lane group
            a0 += f.x * wcol[i0 * 4 + 0].x;  a1 += f.x * wcol[i0 * 4 + 0].y;
            a0 += f.y * wcol[i0 * 4 + 1].x;  a1 += f.y * wcol[i0 * 4 + 1].y;
            a0 += f.z * wcol[i0 * 4 + 2].x;  a1 += f.z * wcol[i0 * 4 + 2].y;
            a0 += f.w * wcol[i0 * 4 + 3].x;  a1 += f.w * wcol[i0 * 4 + 3].y;
        }

        // lanes 0..15 -> 16 consecutive dwords = 64B contiguous per rule
        __half2 h = __floats2half2_rn(a0, a1);
        unsafeAtomicAdd(acc + (size_t)orow * 16 + j, h);
    }
}

// ---------------------------------------------------------------------------
// unpack: out[o][2j..2j+1] = float(acc) + bias
// ---------------------------------------------------------------------------
__global__ __launch_bounds__(256) void unpack_kernel(
    const __half2* __restrict__ acc, const float* __restrict__ bias,
    float* __restrict__ out)
{
    int t = blockIdx.x * 256 + threadIdx.x;      // __half2 index
    if (t >= ACC_WORDS) return;
    const int j = t & 15;
    const float2 v = __half22float2(acc[t]);
    const float2 b = reinterpret_cast<const float2*>(bias)[j];
    float2 o;
    o.x = v.x + b.x;
    o.y = v.y + b.y;
    reinterpret_cast<float2*>(out)[t] = o;
}

// ===========================================================================
// Fallback path (ws too small): round-2 f32 atomic version
// ===========================================================================
__global__ __launch_bounds__(256) void init_out_kernel(
    const float* __restrict__ bias, float* __restrict__ out)
{
    int idx = blockIdx.x * 256 + threadIdx.x;
    const int total4 = N_OUT_SZ * NC / 4;
    if (idx >= total4) return;
    int c0 = (idx * 4) & (NC - 1);
    float4 b;
    b.x = bias[c0 + 0]; b.y = bias[c0 + 1]; b.z = bias[c0 + 2]; b.w = bias[c0 + 3];
    reinterpret_cast<float4*>(out)[idx] = b;
}

__global__ __launch_bounds__(256) void conv_scatter_kernel(
    const float* __restrict__ feat, const float* __restrict__ weight,
    const int* __restrict__ in_idx, const int* __restrict__ out_idx,
    float* __restrict__ out)
{
    __shared__ float Wlds[NC * NC];
    const int k  = blockIdx.y;
    const int c  = threadIdx.x & (NC - 1);
    const int rg = threadIdx.x >> 5;
    for (int t = threadIdx.x; t < NC * NC; t += 256)
        Wlds[t] = weight[k * NC * NC + t];
    __syncthreads();
    float wcol[NC];
#pragma unroll
    for (int i = 0; i < NC; ++i) wcol[i] = Wlds[i * NC + c];
    const int rbase = blockIdx.x * RPB;
    for (int rr = rg; rr < RPB; rr += 8) {
        const int r = rbase + rr;
        const int irow = in_idx[k * R_RULES + r];
        const int orow = out_idx[k * R_RULES + r];
        const float4* fv = reinterpret_cast<const float4*>(feat + (size_t)irow * NC);
        float acc = 0.0f;
#pragma unroll
        for (int i0 = 0; i0 < 8; ++i0) {
            const float4 f = fv[i0];
            acc += f.x * wcol[i0 * 4 + 0];
            acc += f.y * wcol[i0 * 4 + 1];
            acc += f.z * wcol[i0 * 4 + 2];
            acc += f.w * wcol[i0 * 4 + 3];
        }
        atomicAdd(out + (size_t)orow * NC + c, acc);
    }
}

// ---------------------------------------------------------------------------
extern "C" void kernel_launch(void* const* d_in, const int* in_sizes, int n_in,
                              void* d_out, int out_size, void* d_ws, size_t ws_size,
                              hipStream_t stream)
{
    const float* feat    = (const float*)d_in[0];
    const float* weight  = (const float*)d_in[1];
    const float* bias    = (const float*)d_in[2];
    const int*   in_idx  = (const int*)d_in[3];
    const int*   out_idx = (const int*)d_in[4];
    float*       out     = (float*)d_out;

    if (ws_size >= WS_NEEDED) {
        __half2* acc = (__half2*)d_ws;

        {   // zero f16 accumulators
            int total = ACC_WORDS / 4;
            zero_ws_kernel<<<(total + 255) / 256, 256, 0, stream>>>((uint4*)d_ws);
        }
        {   // packed-f16 atomic scatter
            dim3 grid(R_RULES / RPB, K_OFF);
            conv_scatter_f16_kernel<<<grid, 256, 0, stream>>>(
                feat, weight, in_idx, out_idx, acc);
        }
        {   // unpack to f32 + bias
            unpack_kernel<<<ACC_WORDS / 256, 256, 0, stream>>>(acc, bias, out);
        }
    } else {
        // fallback: f32 atomic scatter
        {
            int total4 = N_OUT_SZ * NC / 4;
            init_out_kernel<<<(total4 + 255) / 256, 256, 0, stream>>>(bias, out);
        }
        {
            dim3 grid(R_RULES / RPB, K_OFF);
            conv_scatter_kernel<<<grid, 256, 0, stream>>>(feat, weight, in_idx, out_idx, out);
        }
    }
}

// Round 5
// 632.796 us; speedup vs baseline: 1.2239x; 1.0021x over previous
//
#include <hip/hip_runtime.h>
#include <hip/hip_fp16.h>

#define N_IN_SZ   400000
#define N_OUT_SZ  200000
#define K_OFF     27
#define R_RULES   200000
#define NC        32
#define RPB       64
#define TOTAL_E   (K_OFF * R_RULES)     // 5,400,000 entries

typedef unsigned int u32;

// ---------------- ws layout (bytes) ----------------
// prodS  : __half2[TOTAL_E * 16]   = 345,600,000
// cnt    : u32[N_OUT]              =     800,000
// start  : u32[N_OUT]              =     800,000
// cursor : u32[N_OUT]              =     800,000
// bsum   : u32[256]                =       1,024
// boff   : u32[256]                =       1,024
#define PRODS_OFF   0
#define CNT_OFF     345600000ull
#define START_OFF   (CNT_OFF + 800000ull)
#define CURSOR_OFF  (START_OFF + 800000ull)
#define BSUM_OFF    (CURSOR_OFF + 800000ull)
#define BOFF_OFF    (BSUM_OFF + 1024ull)
#define WS_SORT_NEEDED (BOFF_OFF + 1024ull)

#define N_CNT4      50000               // N_OUT/4 uint4 counters
#define NBLK_SCAN   196                 // ceil(50000/256)

// fallback (R4) ws need: __half2 acc[N_OUT*16]
#define ACC_WORDS  (N_OUT_SZ * 16)
#define WS_F16_NEEDED  ((size_t)ACC_WORDS * 4)

// ===========================================================================
// sort pipeline
// ===========================================================================
__global__ __launch_bounds__(256) void zero_cnt_kernel(uint4* __restrict__ cnt4)
{
    int i = blockIdx.x * 256 + threadIdx.x;
    if (i < N_CNT4) cnt4[i] = make_uint4(0, 0, 0, 0);
}

__global__ __launch_bounds__(256) void hist_kernel(
    const uint4* __restrict__ oidx4, u32* __restrict__ cnt)
{
    int i = blockIdx.x * 256 + threadIdx.x;
    if (i < TOTAL_E / 4) {
        uint4 v = oidx4[i];
        atomicAdd(&cnt[v.x], 1u);
        atomicAdd(&cnt[v.y], 1u);
        atomicAdd(&cnt[v.z], 1u);
        atomicAdd(&cnt[v.w], 1u);
    }
}

// per-block sums of 1024-counter chunks
__global__ __launch_bounds__(256) void blocksum_kernel(
    const uint4* __restrict__ cnt4, u32* __restrict__ bsum)
{
    int i4 = blockIdx.x * 256 + threadIdx.x;
    u32 s = 0;
    if (i4 < N_CNT4) {
        uint4 c = cnt4[i4];
        s = c.x + c.y + c.z + c.w;
    }
    int lane = threadIdx.x & 63;
#pragma unroll
    for (int off = 32; off > 0; off >>= 1)
        s += __shfl_down(s, off);
    __shared__ u32 ws[4];
    int wid = threadIdx.x >> 6;
    if (lane == 0) ws[wid] = s;
    __syncthreads();
    if (threadIdx.x == 0)
        bsum[blockIdx.x] = ws[0] + ws[1] + ws[2] + ws[3];
}

// exclusive scan of NBLK_SCAN block sums (single block)
__global__ __launch_bounds__(256) void scanblk_kernel(
    const u32* __restrict__ bsum, u32* __restrict__ boff)
{
    __shared__ u32 lds[NBLK_SCAN];
    int t = threadIdx.x;
    if (t < NBLK_SCAN) lds[t] = bsum[t];
    __syncthreads();
    if (t == 0) {
        u32 run = 0;
        for (int i = 0; i < NBLK_SCAN; ++i) { u32 v = lds[i]; lds[i] = run; run += v; }
    }
    __syncthreads();
    if (t < NBLK_SCAN) boff[t] = lds[t];
}

// per-counter exclusive scan -> start[] and cursor[]
__global__ __launch_bounds__(256) void scanwrite_kernel(
    const uint4* __restrict__ cnt4, const u32* __restrict__ boff,
    uint4* __restrict__ start4, uint4* __restrict__ cursor4)
{
    int i4 = blockIdx.x * 256 + threadIdx.x;
    uint4 c = (i4 < N_CNT4) ? cnt4[i4] : make_uint4(0, 0, 0, 0);
    u32 lsum = c.x + c.y + c.z + c.w;
    u32 s = lsum;
    int lane = threadIdx.x & 63;
#pragma unroll
    for (int off = 1; off < 64; off <<= 1) {
        u32 v = __shfl_up(s, off);
        if (lane >= off) s += v;
    }
    __shared__ u32 wsum[4], wbase[4];
    int wid = threadIdx.x >> 6;
    if (lane == 63) wsum[wid] = s;
    __syncthreads();
    if (threadIdx.x == 0) {
        u32 run = 0;
        for (int w = 0; w < 4; ++w) { wbase[w] = run; run += wsum[w]; }
    }
    __syncthreads();
    u32 base = boff[blockIdx.x] + wbase[wid] + (s - lsum);
    if (i4 < N_CNT4) {
        uint4 st;
        st.x = base;
        st.y = st.x + c.x;
        st.z = st.y + c.y;
        st.w = st.z + c.z;
        start4[i4]  = st;
        cursor4[i4] = st;
    }
}

// ===========================================================================
// compute prod rows and store each to its sorted slot (plain stores, no
// accumulation atomics). 16-lane group per rule; lane j = channels (2j,2j+1).
// ===========================================================================
__global__ __launch_bounds__(256) void conv_prod_scatter_kernel(
    const float* __restrict__ feat,     // [N_IN, 32]
    const float* __restrict__ weight,   // [27*32, 32]
    const int*   __restrict__ in_idx,   // [27, R]
    const int*   __restrict__ out_idx,  // [27, R]
    u32*         __restrict__ cursor,   // [N_OUT]
    __half2*     __restrict__ prodS)    // [TOTAL_E, 16]
{
    __shared__ float2 Wlds[NC * 16];
    const int k = blockIdx.y;
    const float2* wg = reinterpret_cast<const float2*>(weight + k * NC * NC);
    for (int t = threadIdx.x; t < NC * 16; t += 256)
        Wlds[t] = wg[t];
    __syncthreads();

    const int j = threadIdx.x & 15;
    const int g = threadIdx.x >> 4;        // 16 rule-groups per block

    float2 wcol[NC];
#pragma unroll
    for (int i = 0; i < NC; ++i)
        wcol[i] = Wlds[i * 16 + j];

    const int rbase = blockIdx.x * RPB;

    // phase 1: issue all 4 cursor atomics up-front (independent, overlapped)
    int irow[4];
    u32 pos[4];
#pragma unroll
    for (int i = 0; i < 4; ++i) {
        const int r = rbase + g + 16 * i;
        const int o = out_idx[k * R_RULES + r];
        irow[i] = in_idx[k * R_RULES + r];
        if (j == 0) pos[i] = atomicAdd(&cursor[o], 1u);
    }

    // phase 2: compute and store
#pragma unroll
    for (int i = 0; i < 4; ++i) {
        const u32 p = (u32)__shfl((int)pos[i], (threadIdx.x & 63) & 48);

        const float4* fv = reinterpret_cast<const float4*>(feat + (size_t)irow[i] * NC);
        float a0 = 0.0f, a1 = 0.0f;
#pragma unroll
        for (int i0 = 0; i0 < 8; ++i0) {
            const float4 f = fv[i0];
            a0 += f.x * wcol[i0 * 4 + 0].x;  a1 += f.x * wcol[i0 * 4 + 0].y;
            a0 += f.y * wcol[i0 * 4 + 1].x;  a1 += f.y * wcol[i0 * 4 + 1].y;
            a0 += f.z * wcol[i0 * 4 + 2].x;  a1 += f.z * wcol[i0 * 4 + 2].y;
            a0 += f.w * wcol[i0 * 4 + 3].x;  a1 += f.w * wcol[i0 * 4 + 3].y;
        }
        prodS[(size_t)p * 16 + j] = __floats2half2_rn(a0, a1);
    }
}

// ===========================================================================
// segmented reduce: out[o][:] = sum of prodS rows [start[o], start[o+1]) + bias
// ===========================================================================
__global__ __launch_bounds__(256) void seg_reduce_kernel(
    const __half2* __restrict__ prodS, const u32* __restrict__ start,
    const float* __restrict__ bias, float* __restrict__ out)
{
    const int j = threadIdx.x & 15;
    const int g = threadIdx.x >> 4;
    const int o = blockIdx.x * 16 + g;           // grid covers N_OUT exactly

    const u32 s = start[o];
    const u32 e = (o < N_OUT_SZ - 1) ? start[o + 1] : (u32)TOTAL_E;

    float a0 = 0.0f, a1 = 0.0f;
    u32 t = s;
    for (; t + 1 < e; t += 2) {
        float2 v0 = __half22float2(prodS[(size_t)t * 16 + j]);
        float2 v1 = __half22float2(prodS[(size_t)(t + 1) * 16 + j]);
        a0 += v0.x + v1.x;
        a1 += v0.y + v1.y;
    }
    if (t < e) {
        float2 v = __half22float2(prodS[(size_t)t * 16 + j]);
        a0 += v.x; a1 += v.y;
    }

    const float2 b = reinterpret_cast<const float2*>(bias)[j];
    float2 ov; ov.x = a0 + b.x; ov.y = a1 + b.y;
    reinterpret_cast<float2*>(out)[(size_t)o * 16 + j] = ov;
}

// ===========================================================================
// Fallback paths
// ===========================================================================
__global__ __launch_bounds__(256) void zero_ws_kernel(uint4* __restrict__ ws)
{
    const int total = ACC_WORDS / 4;
    int idx = blockIdx.x * 256 + threadIdx.x;
    if (idx < total) ws[idx] = make_uint4(0, 0, 0, 0);
}

__global__ __launch_bounds__(256) void conv_scatter_f16_kernel(
    const float* __restrict__ feat, const float* __restrict__ weight,
    const int* __restrict__ in_idx, const int* __restrict__ out_idx,
    __half2* __restrict__ acc)
{
    __shared__ float2 Wlds[NC * 16];
    const int k = blockIdx.y;
    const float2* wg = reinterpret_cast<const float2*>(weight + k * NC * NC);
    for (int t = threadIdx.x; t < NC * 16; t += 256)
        Wlds[t] = wg[t];
    __syncthreads();
    const int j = threadIdx.x & 15;
    const int g = threadIdx.x >> 4;
    float2 wcol[NC];
#pragma unroll
    for (int i = 0; i < NC; ++i) wcol[i] = Wlds[i * 16 + j];
    const int rbase = blockIdx.x * RPB;
    for (int rr = g; rr < RPB; rr += 16) {
        const int r = rbase + rr;
        const int irow = in_idx[k * R_RULES + r];
        const int orow = out_idx[k * R_RULES + r];
        const float4* fv = reinterpret_cast<const float4*>(feat + (size_t)irow * NC);
        float a0 = 0.0f, a1 = 0.0f;
#pragma unroll
        for (int i0 = 0; i0 < 8; ++i0) {
            const float4 f = fv[i0];
            a0 += f.x * wcol[i0 * 4 + 0].x;  a1 += f.x * wcol[i0 * 4 + 0].y;
            a0 += f.y * wcol[i0 * 4 + 1].x;  a1 += f.y * wcol[i0 * 4 + 1].y;
            a0 += f.z * wcol[i0 * 4 + 2].x;  a1 += f.z * wcol[i0 * 4 + 2].y;
            a0 += f.w * wcol[i0 * 4 + 3].x;  a1 += f.w * wcol[i0 * 4 + 3].y;
        }
        unsafeAtomicAdd(acc + (size_t)orow * 16 + j, __floats2half2_rn(a0, a1));
    }
}

__global__ __launch_bounds__(256) void unpack_kernel(
    const __half2* __restrict__ acc, const float* __restrict__ bias,
    float* __restrict__ out)
{
    int t = blockIdx.x * 256 + threadIdx.x;
    if (t >= ACC_WORDS) return;
    const int j = t & 15;
    const float2 v = __half22float2(acc[t]);
    const float2 b = reinterpret_cast<const float2*>(bias)[j];
    float2 o; o.x = v.x + b.x; o.y = v.y + b.y;
    reinterpret_cast<float2*>(out)[t] = o;
}

__global__ __launch_bounds__(256) void init_out_kernel(
    const float* __restrict__ bias, float* __restrict__ out)
{
    int idx = blockIdx.x * 256 + threadIdx.x;
    const int total4 = N_OUT_SZ * NC / 4;
    if (idx >= total4) return;
    int c0 = (idx * 4) & (NC - 1);
    float4 b;
    b.x = bias[c0 + 0]; b.y = bias[c0 + 1]; b.z = bias[c0 + 2]; b.w = bias[c0 + 3];
    reinterpret_cast<float4*>(out)[idx] = b;
}

__global__ __launch_bounds__(256) void conv_scatter_kernel(
    const float* __restrict__ feat, const float* __restrict__ weight,
    const int* __restrict__ in_idx, const int* __restrict__ out_idx,
    float* __restrict__ out)
{
    __shared__ float Wlds[NC * NC];
    const int k  = blockIdx.y;
    const int c  = threadIdx.x & (NC - 1);
    const int rg = threadIdx.x >> 5;
    for (int t = threadIdx.x; t < NC * NC; t += 256)
        Wlds[t] = weight[k * NC * NC + t];
    __syncthreads();
    float wcol[NC];
#pragma unroll
    for (int i = 0; i < NC; ++i) wcol[i] = Wlds[i * NC + c];
    const int rbase = blockIdx.x * RPB;
    for (int rr = rg; rr < RPB; rr += 8) {
        const int r = rbase + rr;
        const int irow = in_idx[k * R_RULES + r];
        const int orow = out_idx[k * R_RULES + r];
        const float4* fv = reinterpret_cast<const float4*>(feat + (size_t)irow * NC);
        float acc = 0.0f;
#pragma unroll
        for (int i0 = 0; i0 < 8; ++i0) {
            const float4 f = fv[i0];
            acc += f.x * wcol[i0 * 4 + 0];
            acc += f.y * wcol[i0 * 4 + 1];
            acc += f.z * wcol[i0 * 4 + 2];
            acc += f.w * wcol[i0 * 4 + 3];
        }
        atomicAdd(out + (size_t)orow * NC + c, acc);
    }
}

// ---------------------------------------------------------------------------
extern "C" void kernel_launch(void* const* d_in, const int* in_sizes, int n_in,
                              void* d_out, int out_size, void* d_ws, size_t ws_size,
                              hipStream_t stream)
{
    const float* feat    = (const float*)d_in[0];
    const float* weight  = (const float*)d_in[1];
    const float* bias    = (const float*)d_in[2];
    const int*   in_idx  = (const int*)d_in[3];
    const int*   out_idx = (const int*)d_in[4];
    float*       out     = (float*)d_out;

    if (ws_size >= WS_SORT_NEEDED) {
        char* ws = (char*)d_ws;
        __half2* prodS  = (__half2*)(ws + PRODS_OFF);
        u32*     cnt    = (u32*)(ws + CNT_OFF);
        u32*     start  = (u32*)(ws + START_OFF);
        u32*     cursor = (u32*)(ws + CURSOR_OFF);
        u32*     bsum   = (u32*)(ws + BSUM_OFF);
        u32*     boff   = (u32*)(ws + BOFF_OFF);

        zero_cnt_kernel<<<NBLK_SCAN, 256, 0, stream>>>((uint4*)cnt);
        hist_kernel<<<(TOTAL_E / 4 + 255) / 256, 256, 0, stream>>>(
            (const uint4*)out_idx, cnt);
        blocksum_kernel<<<NBLK_SCAN, 256, 0, stream>>>((const uint4*)cnt, bsum);
        scanblk_kernel<<<1, 256, 0, stream>>>(bsum, boff);
        scanwrite_kernel<<<NBLK_SCAN, 256, 0, stream>>>(
            (const uint4*)cnt, boff, (uint4*)start, (uint4*)cursor);

        {
            dim3 grid(R_RULES / RPB, K_OFF);
            conv_prod_scatter_kernel<<<grid, 256, 0, stream>>>(
                feat, weight, in_idx, out_idx, cursor, prodS);
        }
        seg_reduce_kernel<<<N_OUT_SZ / 16, 256, 0, stream>>>(prodS, start, bias, out);
    } else if (ws_size >= WS_F16_NEEDED) {
        __half2* acc = (__half2*)d_ws;
        zero_ws_kernel<<<(ACC_WORDS / 4 + 255) / 256, 256, 0, stream>>>((uint4*)d_ws);
        dim3 grid(R_RULES / RPB, K_OFF);
        conv_scatter_f16_kernel<<<grid, 256, 0, stream>>>(feat, weight, in_idx, out_idx, acc);
        unpack_kernel<<<ACC_WORDS / 256, 256, 0, stream>>>(acc, bias, out);
    } else {
        int total4 = N_OUT_SZ * NC / 4;
        init_out_kernel<<<(total4 + 255) / 256, 256, 0, stream>>>(bias, out);
        dim3 grid(R_RULES / RPB, K_OFF);
        conv_scatter_kernel<<<grid, 256, 0, stream>>>(feat, weight, in_idx, out_idx, out);
    }
}